// Round 8
// baseline (236.033 us; speedup 1.0000x reference)
//
#include <hip/hip_runtime.h>
#include <hip/hip_bf16.h>

// AgreementRouting, 2-kernel plan + DPP cross-lane + software-pipelined
// (2-stage prefetch) hot loops. B=128, IC=1152, OC=10, D=16, 3 iters, f32.
//
// A (1024 blk x 256 thr): read f32 u ONCE (non-temporal) -> bf16 copy u16 +
//    per-block s0 partials. 2-stage prefetch over its 9 slices.
// B (128 blk x 1024 thr, one block per b): sum partials -> v1; 3 phases, each
//    streams u16[b] (368KB) with a 2-stage prefetched 18-slice loop,
//    block-local LDS reduction, in-LDS squash.
//    Logits: bb_T = b_in + <u, sum_{t<T} v_t> (linearity).
//
// R8 fix: __launch_bounds__(1024, 4) on b_kernel. 1024 thr = 16 waves/CU =
// 4 waves/EU; per-SIMD VGPR pool 512/lane -> cap 128 VGPR (vs default 64,
// which spilled R7's pipeline state to scratch: 151MB writes, 244us).
//
// Cross-lane: all DPP (VALU pipe) in hot loops. Lane scheme per 16-lane
// group (slice = 10x16 f32): l=tid&15, h=l>>3. Lane owns
// (j=2k+h, d=2(l&7)..2(l&7)+1), k=0..4 == float offset 32k+2l.

#define B_    128
#define IC_   1152
#define OC_   10
#define ROW_  160
#define WPS_  80          // bf16 dwords per slice
#define APARTS 8
#define ASPB   144        // slices per A-part
#define AUPB   9          // slices per 16-lane group in A
#define BGRP   64         // 16-lane groups in B (1024 thr)
#define BUPB   18         // slices per group in B (1152/64)
#define BNW    16         // waves in B

typedef float v2f __attribute__((ext_vector_type(2)));

__device__ __forceinline__ float bf_lo(uint32_t w) { return __uint_as_float(w << 16); }
__device__ __forceinline__ float bf_hi(uint32_t w) { return __uint_as_float(w & 0xffff0000u); }

template<int CTRL>
__device__ __forceinline__ float dppf(float x) {
    return __int_as_float(__builtin_amdgcn_update_dpp(
        0, __float_as_int(x), CTRL, 0xF, 0xF, true));
}
// sum over the 8 lanes sharing h (lane bits 0..2), replicated
__device__ __forceinline__ float dpp_sum8(float x) {
    x += dppf<0xB1>(x);    // quad_perm [1,0,3,2]  (xor1)
    x += dppf<0x4E>(x);    // quad_perm [2,3,0,1]  (xor2)
    x += dppf<0x141>(x);   // row_half_mirror      (cross-quad within 8)
    return x;
}
// softmax over 10 logits own[5] (lane h owns j=2k+h); returns inv-denominator.
__device__ __forceinline__ float softmax10(float own[5]) {
    float m = own[0];
#pragma unroll
    for (int k = 1; k < 5; ++k) m = fmaxf(m, own[k]);
    m = fmaxf(m, dppf<0x128>(m));          // row_ror:8 == xor8 within 16
    float sum = 0.f;
#pragma unroll
    for (int k = 0; k < 5; ++k) { own[k] = __expf(own[k] - m); sum += own[k]; }
    sum += dppf<0x128>(sum);
    return 1.f / sum;
}

// ---------------- Kernel A ----------------
__global__ __launch_bounds__(256) void a_kernel(
    const float* __restrict__ u, const float* __restrict__ b_in,
    uint32_t* __restrict__ u16, float* __restrict__ s_part)
{
    const int bid = blockIdx.x, tid = threadIdx.x;
    const int l = tid & 15, h = l >> 3, g = tid >> 4;
    const int b = bid >> 3, part = bid & 7;
    const int wave = tid >> 6, lane = tid & 63;
    __shared__ float red[4][ROW_];

    float2 sc[5];
#pragma unroll
    for (int k = 0; k < 5; ++k) { sc[k].x = 0.f; sc[k].y = 0.f; }

    const int i_base = part * ASPB + g;

#define A_LOAD(UV, BBF, uu) do {                                            \
        const int i_ = i_base + (uu) * 16;                                  \
        const v2f* up_ = (const v2f*)(u + (size_t)(b * IC_ + i_) * ROW_ + 2 * l); \
        _Pragma("unroll")                                                   \
        for (int k = 0; k < 5; ++k) UV[k] = __builtin_nontemporal_load(up_ + 16 * k); \
        _Pragma("unroll")                                                   \
        for (int k = 0; k < 5; ++k) BBF[k] = b_in[i_ * OC_ + 2 * k + h];    \
    } while (0)

#define A_COMP(UV, BBF, uu) do {                                            \
        const int i_ = i_base + (uu) * 16;                                  \
        uint32_t* wp_ = u16 + (size_t)(b * IC_ + i_) * WPS_;                \
        _Pragma("unroll")                                                   \
        for (int k = 0; k < 5; ++k) {                                       \
            __hip_bfloat16 bx = __float2bfloat16(UV[k].x);                  \
            __hip_bfloat16 by = __float2bfloat16(UV[k].y);                  \
            wp_[16 * k + l] = ((uint32_t)(*(const uint16_t*)&by) << 16) |   \
                               (uint32_t)(*(const uint16_t*)&bx);           \
        }                                                                   \
        float own[5];                                                       \
        _Pragma("unroll")                                                   \
        for (int k = 0; k < 5; ++k) own[k] = BBF[k];                        \
        const float inv = softmax10(own);                                   \
        _Pragma("unroll")                                                   \
        for (int k = 0; k < 5; ++k) {                                       \
            float c = own[k] * inv;                                         \
            sc[k].x += c * UV[k].x; sc[k].y += c * UV[k].y;                 \
        }                                                                   \
    } while (0)

    v2f uvA[5], uvB[5];
    float bbA[5], bbB[5];
    A_LOAD(uvA, bbA, 0);
#pragma unroll
    for (int uu = 0; uu < 8; uu += 2) {
        A_LOAD(uvB, bbB, uu + 1);
        A_COMP(uvA, bbA, uu);
        A_LOAD(uvA, bbA, uu + 2);
        A_COMP(uvB, bbB, uu + 1);
    }
    A_COMP(uvA, bbA, 8);
#undef A_LOAD
#undef A_COMP

#pragma unroll
    for (int k = 0; k < 5; ++k) {
        sc[k].x += __shfl_xor(sc[k].x, 16); sc[k].y += __shfl_xor(sc[k].y, 16);
        sc[k].x += __shfl_xor(sc[k].x, 32); sc[k].y += __shfl_xor(sc[k].y, 32);
    }
    if (lane < 16) {
#pragma unroll
        for (int k = 0; k < 5; ++k)
            *(float2*)&red[wave][32 * k + 2 * l] = sc[k];
    }
    __syncthreads();
    if (tid < ROW_) {
        float t = red[0][tid] + red[1][tid] + red[2][tid] + red[3][tid];
        s_part[(size_t)(b * APARTS + part) * ROW_ + tid] = t;
    }
}

// ---------------- Kernel B ----------------
__global__ __launch_bounds__(1024, 4) void b_kernel(
    const uint32_t* __restrict__ u16, const float* __restrict__ b_in,
    const float* __restrict__ s_part, float* __restrict__ out)
{
    const int b = blockIdx.x, tid = threadIdx.x;
    const int l = tid & 15, h = l >> 3, g = tid >> 4;
    const int wave = tid >> 6, lane = tid & 63;

    __shared__ float red[BNW][ROW_];
    __shared__ float v_lds[ROW_];

    float vsum = 0.f;    // valid for tid<ROW_
    if (tid < ROW_) {
        const float* sp = s_part + (size_t)b * APARTS * ROW_;
        float x = 0.f;
#pragma unroll
        for (int p = 0; p < APARTS; ++p) x += sp[p * ROW_ + tid];
        float sq = x * x;
        sq += __shfl_xor(sq, 1, 16);
        sq += __shfl_xor(sq, 2, 16);
        sq += __shfl_xor(sq, 4, 16);
        sq += __shfl_xor(sq, 8, 16);
        vsum = (sq / (1.f + sq)) * x * rsqrtf(sq + 1e-8f);
        v_lds[tid] = vsum;
    }
    __syncthreads();

    for (int T = 1; T <= 3; ++T) {
        float2 vv[5];
#pragma unroll
        for (int k = 0; k < 5; ++k)
            vv[k] = *(const float2*)&v_lds[32 * k + 2 * l];

        float2 sc[5];
#pragma unroll
        for (int k = 0; k < 5; ++k) { sc[k].x = 0.f; sc[k].y = 0.f; }

#define B_LOAD(UW, BBF, uu) do {                                            \
        const int i_ = (uu) * BGRP + g;                                     \
        const uint32_t* wp_ = u16 + (size_t)(b * IC_ + i_) * WPS_;          \
        _Pragma("unroll")                                                   \
        for (int k = 0; k < 5; ++k) UW[k] = wp_[16 * k + l];                \
        _Pragma("unroll")                                                   \
        for (int k = 0; k < 5; ++k) BBF[k] = b_in[i_ * OC_ + 2 * k + h];    \
    } while (0)

#define B_COMP(UW, BBF) do {                                                \
        float own[5];                                                       \
        _Pragma("unroll")                                                   \
        for (int k = 0; k < 5; ++k) {                                       \
            float pd = bf_lo(UW[k]) * vv[k].x + bf_hi(UW[k]) * vv[k].y;     \
            own[k] = BBF[k] + dpp_sum8(pd);                                 \
        }                                                                   \
        const float inv = softmax10(own);                                   \
        _Pragma("unroll")                                                   \
        for (int k = 0; k < 5; ++k) {                                       \
            float c = own[k] * inv;                                         \
            sc[k].x += c * bf_lo(UW[k]); sc[k].y += c * bf_hi(UW[k]);       \
        }                                                                   \
    } while (0)

        uint32_t uwA[5], uwB[5];
        float bbA[5], bbB[5];
        B_LOAD(uwA, bbA, 0);
#pragma unroll
        for (int uu = 0; uu < BUPB; uu += 2) {
            B_LOAD(uwB, bbB, uu + 1);
            B_COMP(uwA, bbA);
            if (uu + 2 < BUPB) B_LOAD(uwA, bbA, uu + 2);
            B_COMP(uwB, bbB);
        }
#undef B_LOAD
#undef B_COMP

#pragma unroll
        for (int k = 0; k < 5; ++k) {
            sc[k].x += __shfl_xor(sc[k].x, 16); sc[k].y += __shfl_xor(sc[k].y, 16);
            sc[k].x += __shfl_xor(sc[k].x, 32); sc[k].y += __shfl_xor(sc[k].y, 32);
        }
        if (lane < 16) {
#pragma unroll
            for (int k = 0; k < 5; ++k)
                *(float2*)&red[wave][32 * k + 2 * l] = sc[k];
        }
        __syncthreads();
        if (tid < ROW_) {
            float x = 0.f;
#pragma unroll
            for (int w = 0; w < BNW; ++w) x += red[w][tid];
            float sq = x * x;
            sq += __shfl_xor(sq, 1, 16);
            sq += __shfl_xor(sq, 2, 16);
            sq += __shfl_xor(sq, 4, 16);
            sq += __shfl_xor(sq, 8, 16);
            float v = (sq / (1.f + sq)) * x * rsqrtf(sq + 1e-8f);
            if (T < 3) {
                vsum += v;
                v_lds[tid] = vsum;
            } else {
                out[b * ROW_ + tid] = v;
            }
        }
        __syncthreads();
    }
}

extern "C" void kernel_launch(void* const* d_in, const int* in_sizes, int n_in,
                              void* d_out, int out_size, void* d_ws, size_t ws_size,
                              hipStream_t stream) {
    const float* u    = (const float*)d_in[0];
    const float* b_in = (const float*)d_in[1];
    float* out = (float*)d_out;

    float*    s_part = (float*)d_ws;                          // 128*8*160 f32
    uint32_t* u16    = (uint32_t*)(s_part + B_ * APARTS * ROW_); // 47.2 MB

    a_kernel<<<dim3(B_ * APARTS), dim3(256), 0, stream>>>(u, b_in, u16, s_part);
    b_kernel<<<dim3(B_), dim3(1024), 0, stream>>>(u16, b_in, s_part, out);
}

// Round 9
// 75.920 us; speedup vs baseline: 3.1090x; 3.1090x over previous
//
#include <hip/hip_runtime.h>
#include <hip/hip_bf16.h>

// AgreementRouting, 2-kernel plan + DPP cross-lane + software-pipelined
// hot loops. B=128, IC=1152, OC=10, D=16, 3 iters, f32 in/out.
//
// A (1024 blk x 256 thr): read f32 u ONCE (non-temporal) -> bf16 copy u16 +
//    per-block s0 partials. 2-stage prefetch over its 9 slices.
// B (128 blk x 1024 thr, one block per b): sum partials -> v1; 3 phases, each
//    streams u16[b] (368KB) with a 2-stage prefetched 18-slice loop.
//
// R9 fix (R7/R8 spilled: 64-VGPR cap for 1024-thr blocks, pipeline state
// ~70 regs -> 151MB scratch traffic):
//   1. b_in staged to LDS once (46KB, phase-invariant) -> kills bbA/bbB
//      pipeline buffers and per-slice global loads. Bank-conflict-free:
//      (g*10+2k+h)%32 = 8 distinct banks/wave, broadcast within 8 lanes.
//   2. slice loop NOT unrolled (rotating A/B macros, explicit epilogue) ->
//      no 18 precomputed 64-bit addresses (20KB stride doesn't fold into
//      the 13-bit global offset field).
//   Live regs ~45-50 < 64 -> no spill; 2-deep prefetch finally effective.
//
// Cross-lane: all DPP (VALU pipe) in hot loops. Lane scheme per 16-lane
// group (slice = 10x16 f32): l=tid&15, h=l>>3. Lane owns
// (j=2k+h, d=2(l&7)..2(l&7)+1), k=0..4 == float offset 32k+2l.

#define B_    128
#define IC_   1152
#define OC_   10
#define ROW_  160
#define WPS_  80          // bf16 dwords per slice
#define APARTS 8
#define ASPB   144        // slices per A-part
#define BGRP   64         // 16-lane groups in B (1024 thr)
#define BUPB   18         // slices per group in B (1152/64)
#define BNW    16         // waves in B

typedef float v2f __attribute__((ext_vector_type(2)));

__device__ __forceinline__ float bf_lo(uint32_t w) { return __uint_as_float(w << 16); }
__device__ __forceinline__ float bf_hi(uint32_t w) { return __uint_as_float(w & 0xffff0000u); }

template<int CTRL>
__device__ __forceinline__ float dppf(float x) {
    return __int_as_float(__builtin_amdgcn_update_dpp(
        0, __float_as_int(x), CTRL, 0xF, 0xF, true));
}
// sum over the 8 lanes sharing h (lane bits 0..2), replicated
__device__ __forceinline__ float dpp_sum8(float x) {
    x += dppf<0xB1>(x);    // quad_perm [1,0,3,2]  (xor1)
    x += dppf<0x4E>(x);    // quad_perm [2,3,0,1]  (xor2)
    x += dppf<0x141>(x);   // row_half_mirror      (cross-quad within 8)
    return x;
}
// softmax over 10 logits own[5] (lane h owns j=2k+h); returns inv-denominator.
__device__ __forceinline__ float softmax10(float own[5]) {
    float m = own[0];
#pragma unroll
    for (int k = 1; k < 5; ++k) m = fmaxf(m, own[k]);
    m = fmaxf(m, dppf<0x128>(m));          // row_ror:8 == xor8 within 16
    float sum = 0.f;
#pragma unroll
    for (int k = 0; k < 5; ++k) { own[k] = __expf(own[k] - m); sum += own[k]; }
    sum += dppf<0x128>(sum);
    return 1.f / sum;
}

// ---------------- Kernel A ----------------
__global__ __launch_bounds__(256) void a_kernel(
    const float* __restrict__ u, const float* __restrict__ b_in,
    uint32_t* __restrict__ u16, float* __restrict__ s_part)
{
    const int bid = blockIdx.x, tid = threadIdx.x;
    const int l = tid & 15, h = l >> 3, g = tid >> 4;
    const int b = bid >> 3, part = bid & 7;
    const int wave = tid >> 6, lane = tid & 63;
    __shared__ float red[4][ROW_];

    float2 sc[5];
#pragma unroll
    for (int k = 0; k < 5; ++k) { sc[k].x = 0.f; sc[k].y = 0.f; }

    const int i_base = part * ASPB + g;

#define A_LOAD(UV, BBF, uu) do {                                            \
        const int i_ = i_base + (uu) * 16;                                  \
        const v2f* up_ = (const v2f*)(u + (size_t)(b * IC_ + i_) * ROW_ + 2 * l); \
        _Pragma("unroll")                                                   \
        for (int k = 0; k < 5; ++k) UV[k] = __builtin_nontemporal_load(up_ + 16 * k); \
        _Pragma("unroll")                                                   \
        for (int k = 0; k < 5; ++k) BBF[k] = b_in[i_ * OC_ + 2 * k + h];    \
    } while (0)

#define A_COMP(UV, BBF, uu) do {                                            \
        const int i_ = i_base + (uu) * 16;                                  \
        uint32_t* wp_ = u16 + (size_t)(b * IC_ + i_) * WPS_;                \
        _Pragma("unroll")                                                   \
        for (int k = 0; k < 5; ++k) {                                       \
            __hip_bfloat16 bx = __float2bfloat16(UV[k].x);                  \
            __hip_bfloat16 by = __float2bfloat16(UV[k].y);                  \
            wp_[16 * k + l] = ((uint32_t)(*(const uint16_t*)&by) << 16) |   \
                               (uint32_t)(*(const uint16_t*)&bx);           \
        }                                                                   \
        float own[5];                                                       \
        _Pragma("unroll")                                                   \
        for (int k = 0; k < 5; ++k) own[k] = BBF[k];                        \
        const float inv = softmax10(own);                                   \
        _Pragma("unroll")                                                   \
        for (int k = 0; k < 5; ++k) {                                       \
            float c = own[k] * inv;                                         \
            sc[k].x += c * UV[k].x; sc[k].y += c * UV[k].y;                 \
        }                                                                   \
    } while (0)

    v2f uvA[5], uvB[5];
    float bbA[5], bbB[5];
    A_LOAD(uvA, bbA, 0);
#pragma unroll
    for (int uu = 0; uu < 8; uu += 2) {
        A_LOAD(uvB, bbB, uu + 1);
        A_COMP(uvA, bbA, uu);
        A_LOAD(uvA, bbA, uu + 2);
        A_COMP(uvB, bbB, uu + 1);
    }
    A_COMP(uvA, bbA, 8);
#undef A_LOAD
#undef A_COMP

#pragma unroll
    for (int k = 0; k < 5; ++k) {
        sc[k].x += __shfl_xor(sc[k].x, 16); sc[k].y += __shfl_xor(sc[k].y, 16);
        sc[k].x += __shfl_xor(sc[k].x, 32); sc[k].y += __shfl_xor(sc[k].y, 32);
    }
    if (lane < 16) {
#pragma unroll
        for (int k = 0; k < 5; ++k)
            *(float2*)&red[wave][32 * k + 2 * l] = sc[k];
    }
    __syncthreads();
    if (tid < ROW_) {
        float t = red[0][tid] + red[1][tid] + red[2][tid] + red[3][tid];
        s_part[(size_t)(b * APARTS + part) * ROW_ + tid] = t;
    }
}

// ---------------- Kernel B ----------------
__global__ __launch_bounds__(1024) void b_kernel(
    const uint32_t* __restrict__ u16, const float* __restrict__ b_in,
    const float* __restrict__ s_part, float* __restrict__ out)
{
    const int b = blockIdx.x, tid = threadIdx.x;
    const int l = tid & 15, h = l >> 3, g = tid >> 4;
    const int wave = tid >> 6, lane = tid & 63;

    __shared__ float red[BNW][ROW_];
    __shared__ float v_lds[ROW_];
    __shared__ float b_lds[IC_ * OC_];   // 46080 B, phase-invariant

    // stage b_in -> LDS (once)
    {
        const float4* src = (const float4*)b_in;
        float4* dst = (float4*)b_lds;
#pragma unroll
        for (int it = 0; it < 3; ++it) {
            int idx = it * 1024 + tid;
            if (idx < IC_ * OC_ / 4) dst[idx] = src[idx];
        }
    }

    float vsum = 0.f;    // valid for tid<ROW_
    if (tid < ROW_) {
        const float* sp = s_part + (size_t)b * APARTS * ROW_;
        float x = 0.f;
#pragma unroll
        for (int p = 0; p < APARTS; ++p) x += sp[p * ROW_ + tid];
        float sq = x * x;
        sq += __shfl_xor(sq, 1, 16);
        sq += __shfl_xor(sq, 2, 16);
        sq += __shfl_xor(sq, 4, 16);
        sq += __shfl_xor(sq, 8, 16);
        vsum = (sq / (1.f + sq)) * x * rsqrtf(sq + 1e-8f);
        v_lds[tid] = vsum;
    }
    __syncthreads();

    for (int T = 1; T <= 3; ++T) {
        float2 vv[5];
#pragma unroll
        for (int k = 0; k < 5; ++k)
            vv[k] = *(const float2*)&v_lds[32 * k + 2 * l];

        float2 sc[5];
#pragma unroll
        for (int k = 0; k < 5; ++k) { sc[k].x = 0.f; sc[k].y = 0.f; }

#define B_LOAD(UW, uu) do {                                                 \
        const int i_ = (uu) * BGRP + g;                                     \
        const uint32_t* wp_ = u16 + (size_t)(b * IC_ + i_) * WPS_;          \
        _Pragma("unroll")                                                   \
        for (int k = 0; k < 5; ++k) UW[k] = wp_[16 * k + l];                \
    } while (0)

#define B_COMP(UW, uu) do {                                                 \
        const int i_ = (uu) * BGRP + g;                                     \
        float own[5];                                                       \
        _Pragma("unroll")                                                   \
        for (int k = 0; k < 5; ++k) own[k] = b_lds[i_ * OC_ + 2 * k + h];   \
        _Pragma("unroll")                                                   \
        for (int k = 0; k < 5; ++k) {                                       \
            float pd = bf_lo(UW[k]) * vv[k].x + bf_hi(UW[k]) * vv[k].y;     \
            own[k] += dpp_sum8(pd);                                         \
        }                                                                   \
        const float inv = softmax10(own);                                   \
        _Pragma("unroll")                                                   \
        for (int k = 0; k < 5; ++k) {                                       \
            float c = own[k] * inv;                                         \
            sc[k].x += c * bf_lo(UW[k]); sc[k].y += c * bf_hi(UW[k]);       \
        }                                                                   \
    } while (0)

        uint32_t uwA[5], uwB[5];
        B_LOAD(uwA, 0);
#pragma clang loop unroll(disable)
        for (int uu = 0; uu < BUPB - 2; uu += 2) {
            B_LOAD(uwB, uu + 1);
            B_COMP(uwA, uu);
            B_LOAD(uwA, uu + 2);
            B_COMP(uwB, uu + 1);
        }
        B_LOAD(uwB, BUPB - 1);
        B_COMP(uwA, BUPB - 2);
        B_COMP(uwB, BUPB - 1);
#undef B_LOAD
#undef B_COMP

#pragma unroll
        for (int k = 0; k < 5; ++k) {
            sc[k].x += __shfl_xor(sc[k].x, 16); sc[k].y += __shfl_xor(sc[k].y, 16);
            sc[k].x += __shfl_xor(sc[k].x, 32); sc[k].y += __shfl_xor(sc[k].y, 32);
        }
        if (lane < 16) {
#pragma unroll
            for (int k = 0; k < 5; ++k)
                *(float2*)&red[wave][32 * k + 2 * l] = sc[k];
        }
        __syncthreads();
        if (tid < ROW_) {
            float x = 0.f;
#pragma unroll
            for (int w = 0; w < BNW; ++w) x += red[w][tid];
            float sq = x * x;
            sq += __shfl_xor(sq, 1, 16);
            sq += __shfl_xor(sq, 2, 16);
            sq += __shfl_xor(sq, 4, 16);
            sq += __shfl_xor(sq, 8, 16);
            float v = (sq / (1.f + sq)) * x * rsqrtf(sq + 1e-8f);
            if (T < 3) {
                vsum += v;
                v_lds[tid] = vsum;
            } else {
                out[b * ROW_ + tid] = v;
            }
        }
        __syncthreads();
    }
}

extern "C" void kernel_launch(void* const* d_in, const int* in_sizes, int n_in,
                              void* d_out, int out_size, void* d_ws, size_t ws_size,
                              hipStream_t stream) {
    const float* u    = (const float*)d_in[0];
    const float* b_in = (const float*)d_in[1];
    float* out = (float*)d_out;

    float*    s_part = (float*)d_ws;                          // 128*8*160 f32
    uint32_t* u16    = (uint32_t*)(s_part + B_ * APARTS * ROW_); // 47.2 MB

    a_kernel<<<dim3(B_ * APARTS), dim3(256), 0, stream>>>(u, b_in, u16, s_part);
    b_kernel<<<dim3(B_), dim3(1024), 0, stream>>>(u16, b_in, s_part, out);
}